// Round 1
// baseline (365.020 us; speedup 1.0000x reference)
//
#include <hip/hip_runtime.h>
#include <math.h>
#include <stdint.h>

#define LSEQ 8192
#define DIN  512
#define NB   8
#define NO   1024

typedef __bf16 bf16x8 __attribute__((ext_vector_type(8)));
typedef float f32x16 __attribute__((ext_vector_type(16)));

__device__ __forceinline__ uint32_t pack_bf16_rne(float lo, float hi) {
    uint32_t ul = __builtin_bit_cast(uint32_t, lo);
    uint32_t uh = __builtin_bit_cast(uint32_t, hi);
    ul += 0x7FFFu + ((ul >> 16) & 1u);
    uh += 0x7FFFu + ((uh >> 16) & 1u);
    return (ul >> 16) | (uh & 0xFFFF0000u);
}
__device__ __forceinline__ float bf16_lo(uint32_t w) {
    return __builtin_bit_cast(float, w << 16);
}
__device__ __forceinline__ float bf16_hi(uint32_t w) {
    return __builtin_bit_cast(float, w & 0xFFFF0000u);
}

// async global->LDS, 16B per lane; LDS dest = wave-uniform base + lane*16
__device__ __forceinline__ void gl_lds16(const void* g, void* l) {
    __builtin_amdgcn_global_load_lds(
        (const __attribute__((address_space(1))) void*)g,
        (__attribute__((address_space(3))) void*)l, 16, 0, 0);
}

// ---------------- Kernel 1: weight norm -> bf16 (pair-packed) -------------
__global__ void norm_kernel(const float* __restrict__ W, uint32_t* __restrict__ Wnb) {
    const int o = blockIdx.x;
    const int lane = threadIdx.x;  // 0..63
    const float* row = W + (size_t)o * DIN;
    float4 v0 = *(const float4*)(row + lane * 4);
    float4 v1 = *(const float4*)(row + 256 + lane * 4);
    float s = v0.x * v0.x + v0.y * v0.y + v0.z * v0.z + v0.w * v0.w
            + v1.x * v1.x + v1.y * v1.y + v1.z * v1.z + v1.w * v1.w;
#pragma unroll
    for (int m = 32; m; m >>= 1) s += __shfl_xor(s, m, 64);
    const float sq = 22.62741699796952f;  // sqrt(512)
    const float scale = 1.0f / ((1e-4f + sqrtf(s) / sq) * sq);
    uint2 w0, w1;
    w0.x = pack_bf16_rne(v0.x * scale, v0.y * scale);
    w0.y = pack_bf16_rne(v0.z * scale, v0.w * scale);
    w1.x = pack_bf16_rne(v1.x * scale, v1.y * scale);
    w1.y = pack_bf16_rne(v1.z * scale, v1.w * scale);
    *(uint2*)&Wnb[o * 256 + lane * 2] = w0;
    *(uint2*)&Wnb[o * 256 + 128 + lane * 2] = w1;
}

// ---------------- Kernel 1b: x fp32 -> pair-packed bf16, tile-transposed ---
// xpT word ((b*64+lt)*128 + l')*256 + k2 =
//   bf16(x[b][2k2][lt*128+l']) | bf16(x[b][2k2+1][lt*128+l']) << 16
// Block handles one (b, lt, 32-k2 chunk): reads 32 KB coalesced, LDS
// transpose, writes 16 KB coalesced (128B segments).
__global__ __launch_bounds__(256)
void xpack_kernel(const float* __restrict__ x, uint32_t* __restrict__ xp) {
    __shared__ uint32_t sT[32 * 132];  // stride 132: 16B-aligned rows
    const int t  = threadIdx.x;
    const int bx = blockIdx.x;  // lt = bx>>3, ch = bx&7
    const int b  = blockIdx.y;
    const int lt = bx >> 3;
    const int ch = bx & 7;

    const float* xb = x + (size_t)b * DIN * LSEQ + lt * 128;
#pragma unroll
    for (int j = 0; j < 4; ++j) {
        const int idx = j * 256 + t;  // 0..1023
        const int k2l = idx >> 5;     // 0..31
        const int lg  = idx & 31;
        const float* r0 = xb + (size_t)(2 * (ch * 32 + k2l)) * LSEQ + lg * 4;
        float4 a = *(const float4*)r0;
        float4 c = *(const float4*)(r0 + LSEQ);
        uint4 wv;
        wv.x = pack_bf16_rne(a.x, c.x);
        wv.y = pack_bf16_rne(a.y, c.y);
        wv.z = pack_bf16_rne(a.z, c.z);
        wv.w = pack_bf16_rne(a.w, c.w);
        *(uint4*)&sT[k2l * 132 + lg * 4] = wv;
    }
    __syncthreads();
    uint32_t* ob = xp + ((size_t)(b * 64 + lt) * 128) * 256 + ch * 32;
#pragma unroll
    for (int j = 0; j < 4; ++j) {
        const int idx = j * 256 + t;  // 0..1023
        const int lp  = idx >> 3;     // l' 0..127
        const int gq  = idx & 7;      // 4-word k2 group
        uint4 wv;
        wv.x = sT[(gq * 4 + 0) * 132 + lp];
        wv.y = sT[(gq * 4 + 1) * 132 + lp];
        wv.z = sT[(gq * 4 + 2) * 132 + lp];
        wv.w = sT[(gq * 4 + 3) * 132 + lp];
        *(uint4*)&ob[(size_t)lp * 256 + gq * 4] = wv;
    }
}

// ---------------- Kernel 2: bf16 MFMA GEMM, global_load_lds staged --------
// fbp word (b, o2, l) = bf16 fb[b][2*o2][l] | bf16 fb[b][2*o2+1][l] << 16.
// A and B both stage via global_load_lds with pre-swizzled global sources
// (linear LDS dest); fragment reads are ds_read_b128 with matching XOR
// swizzle. One barrier per K-step; next tile prefetched into alt buffer.
__global__ __launch_bounds__(256)
void gemm_kernel(const uint32_t* __restrict__ WnbW, const uint32_t* __restrict__ xp,
                 uint32_t* __restrict__ fbp) {
    __shared__ uint32_t sA[2][2048];  // 2 x 8 KB: 128 rows x 16 words
    __shared__ uint32_t sB[2][2048];  // 2 x 8 KB: 128 cols x 16 words

    const int tid  = threadIdx.x;
    const int lane = tid & 63;
    const int w    = tid >> 6;
    const int wm   = w & 1, wn = w >> 1;

    const int bx  = blockIdx.x;
    const int xcd = bx & 7;
    const int t   = bx >> 3;
    const int o0  = (t & 7) * 128;
    const int ltg = xcd + ((t >> 3) << 3);
    const int l0  = ltg * 128;
    const int b   = blockIdx.y;

    // staging sources: lane L covers (row rowbase + L/4, 16B slot L&3);
    // source k-group pre-swizzled: q = (L&3) ^ (row&3)
    const int rsub = lane >> 2;                    // 0..15
    const int ssub = (lane & 3) ^ (rsub & 3);
    const uint32_t* gA0 = WnbW + (size_t)(o0 + w * 32 + rsub) * 256 + ssub * 4;
    const uint32_t* gA1 = gA0 + (size_t)16 * 256;
    const uint32_t* xptb = xp + (size_t)(b * 64 + ltg) * 32768;
    const uint32_t* gB0 = xptb + (size_t)(w * 32 + rsub) * 256 + ssub * 4;
    const uint32_t* gB1 = gB0 + (size_t)16 * 256;

    f32x16 acc[2][2];
#pragma unroll
    for (int i = 0; i < 2; ++i)
#pragma unroll
        for (int j = 0; j < 2; ++j)
#pragma unroll
            for (int r = 0; r < 16; ++r) acc[i][j][r] = 0.f;

#define STAGE(it, bs)                                      \
    do {                                                   \
        gl_lds16(gA0 + (it) * 16, &sA[bs][w * 512]);       \
        gl_lds16(gA1 + (it) * 16, &sA[bs][w * 512 + 256]); \
        gl_lds16(gB0 + (it) * 16, &sB[bs][w * 512]);       \
        gl_lds16(gB1 + (it) * 16, &sB[bs][w * 512 + 256]); \
    } while (0)

    STAGE(0, 0);
#pragma unroll 2
    for (int it = 0; it < 16; ++it) {
        const int cb = it & 1;
        __syncthreads();  // drains vmcnt(0): buf[cb] ready, prev compute done
        if (it + 1 < 16) STAGE(it + 1, cb ^ 1);
        const uint32_t* cA = sA[cb];
        const uint32_t* cB = sB[cb];
#pragma unroll
        for (int kh = 0; kh < 2; ++kh) {
            const int q = kh * 2 + (lane >> 5);
            bf16x8 af[2], bfr[2];
#pragma unroll
            for (int ms = 0; ms < 2; ++ms) {
                const int m = wm * 64 + ms * 32 + (lane & 31);
                af[ms] = *(const bf16x8*)&cA[m * 16 + ((q ^ (m & 3)) << 2)];
            }
#pragma unroll
            for (int ns = 0; ns < 2; ++ns) {
                const int col = wn * 64 + ns * 32 + (lane & 31);
                bfr[ns] = *(const bf16x8*)&cB[col * 16 + ((q ^ (col & 3)) << 2)];
            }
#pragma unroll
            for (int ms = 0; ms < 2; ++ms)
#pragma unroll
                for (int ns = 0; ns < 2; ++ns)
                    acc[ms][ns] = __builtin_amdgcn_mfma_f32_32x32x16_bf16(
                        af[ms], bfr[ns], acc[ms][ns], 0, 0, 0);
        }
    }
#undef STAGE

    // epilogue: pack adjacent-o pairs (adjacent acc regs) -> one uint32 word
    uint32_t* fbp_b = fbp + (size_t)b * 512 * LSEQ + l0;
#pragma unroll
    for (int ms = 0; ms < 2; ++ms)
#pragma unroll
        for (int ns = 0; ns < 2; ++ns) {
            const f32x16 a = acc[ms][ns];
            const int rb = o0 + wm * 64 + ms * 32 + 4 * (lane >> 5);  // even
            const int cc = wn * 64 + ns * 32 + (lane & 31);
#pragma unroll
            for (int rp = 0; rp < 8; ++rp) {
                const int r = rp * 2;
                const int row = rb + (r & 3) + 8 * (r >> 2);  // even
                fbp_b[(size_t)(row >> 1) * LSEQ + cc] = pack_bf16_rne(a[r], a[r + 1]);
            }
        }
}

// ---------------- Kernel 3: minGRU scan over o-pair-packed bf16 fb --------
__global__ __launch_bounds__(512)
void scan_kernel(const uint32_t* __restrict__ fbp, float* __restrict__ out) {
    __shared__ uint32_t sbuf[8][2048];  // 64 KB
    __shared__ float sA0[8], sB0[8], sA1[8], sB1[8];

    const int bx  = blockIdx.x;  // 0..255
    const int b   = blockIdx.y;
    const int dir = bx >> 7;
    const int p   = bx & 127;
    const int o2h = dir * 256 + p;
    const int o2g = dir * 256 + 128 + p;

    const int t    = threadIdx.x;
    const int lane = t & 63;
    const int w    = t >> 6;

    const uint32_t* hwp = fbp + ((size_t)b * 512 + o2h) * LSEQ + w * 1024;
    const uint32_t* gwp = fbp + ((size_t)b * 512 + o2g) * LSEQ + w * 1024;
    uint32_t* sw = sbuf[w];
    float* swf = (float*)sbuf[w];

#pragma unroll
    for (int i = 0; i < 4; ++i) {
        uint4 v = *(const uint4*)(hwp + i * 256 + lane * 4);
        const uint32_t g = i * 64 + lane;
        const uint32_t gs = g ^ ((g >> 3) & 7);
        *(uint4*)&sw[gs * 4] = v;
    }
#pragma unroll
    for (int i = 0; i < 4; ++i) {
        uint4 v = *(const uint4*)(gwp + i * 256 + lane * 4);
        const uint32_t g = i * 64 + lane;
        const uint32_t gs = g ^ ((g >> 3) & 7);
        *(uint4*)&sw[1024 + gs * 4] = v;
    }
    asm volatile("s_waitcnt lgkmcnt(0)" ::: "memory");

    float av0[16], vv0[16], av1[16], vv1[16];
#pragma unroll
    for (int q = 0; q < 4; ++q) {
        const uint32_t g = lane * 4 + q;
        const uint32_t gs = g ^ ((g >> 3) & 7);
        uint4 hw4 = *(const uint4*)&sw[gs * 4];
        uint4 gw4 = *(const uint4*)&sw[1024 + gs * 4];
        const uint32_t hws[4] = {hw4.x, hw4.y, hw4.z, hw4.w};
        const uint32_t gws[4] = {gw4.x, gw4.y, gw4.z, gw4.w};
#pragma unroll
        for (int s = 0; s < 4; ++s) {
            const int mo = q * 4 + s;
            {
                float g_ = fminf(fmaxf(bf16_lo(gws[s]), -30.f), 30.f);
                float eg = __expf(g_);
                float a  = rsqrtf(fmaf(eg, eg, 1.f));
                float h_ = bf16_lo(hws[s]);
                av0[mo] = a;
                vv0[mo] = a * eg * copysignf(fmaxf(fabsf(h_), 1e-6f), h_);
            }
            {
                float g_ = fminf(fmaxf(bf16_hi(gws[s]), -30.f), 30.f);
                float eg = __expf(g_);
                float a  = rsqrtf(fmaf(eg, eg, 1.f));
                float h_ = bf16_hi(hws[s]);
                av1[mo] = a;
                vv1[mo] = a * eg * copysignf(fmaxf(fabsf(h_), 1e-6f), h_);
            }
        }
    }

    float A0 = 1.f, B0 = 0.f, A1 = 1.f, B1 = 0.f;
    if (dir == 0) {
#pragma unroll
        for (int i = 0; i < 16; ++i) {
            B0 = fmaf(av0[i], B0, vv0[i]); A0 *= av0[i];
            B1 = fmaf(av1[i], B1, vv1[i]); A1 *= av1[i];
        }
    } else {
#pragma unroll
        for (int i = 15; i >= 0; --i) {
            B0 = fmaf(av0[i], B0, vv0[i]); A0 *= av0[i];
            B1 = fmaf(av1[i], B1, vv1[i]); A1 *= av1[i];
        }
    }

    if (dir == 0) {
#pragma unroll
        for (int off = 1; off < 64; off <<= 1) {
            float Ap0 = __shfl_up(A0, (unsigned)off, 64), Bp0 = __shfl_up(B0, (unsigned)off, 64);
            float Ap1 = __shfl_up(A1, (unsigned)off, 64), Bp1 = __shfl_up(B1, (unsigned)off, 64);
            if (lane >= off) {
                B0 = fmaf(A0, Bp0, B0); A0 *= Ap0;
                B1 = fmaf(A1, Bp1, B1); A1 *= Ap1;
            }
        }
        if (lane == 63) { sA0[w] = A0; sB0[w] = B0; sA1[w] = A1; sB1[w] = B1; }
    } else {
#pragma unroll
        for (int off = 1; off < 64; off <<= 1) {
            float Ap0 = __shfl_down(A0, (unsigned)off, 64), Bp0 = __shfl_down(B0, (unsigned)off, 64);
            float Ap1 = __shfl_down(A1, (unsigned)off, 64), Bp1 = __shfl_down(B1, (unsigned)off, 64);
            if (lane + off < 64) {
                B0 = fmaf(A0, Bp0, B0); A0 *= Ap0;
                B1 = fmaf(A1, Bp1, B1); A1 *= Ap1;
            }
        }
        if (lane == 0) { sA0[w] = A0; sB0[w] = B0; sA1[w] = A1; sB1[w] = B1; }
    }
    __syncthreads();
    float WB0 = 0.f, WB1 = 0.f;
    if (dir == 0) {
        for (int wv = 0; wv < w; ++wv) {
            WB0 = fmaf(sA0[wv], WB0, sB0[wv]);
            WB1 = fmaf(sA1[wv], WB1, sB1[wv]);
        }
    } else {
        for (int wv = 7; wv > w; --wv) {
            WB0 = fmaf(sA0[wv], WB0, sB0[wv]);
            WB1 = fmaf(sA1[wv], WB1, sB1[wv]);
        }
    }
    float eA0, eB0, eA1, eB1;
    if (dir == 0) {
        eA0 = __shfl_up(A0, 1u, 64); eB0 = __shfl_up(B0, 1u, 64);
        eA1 = __shfl_up(A1, 1u, 64); eB1 = __shfl_up(B1, 1u, 64);
        if (lane == 0) { eA0 = 1.f; eB0 = 0.f; eA1 = 1.f; eB1 = 0.f; }
    } else {
        eA0 = __shfl_down(A0, 1u, 64); eB0 = __shfl_down(B0, 1u, 64);
        eA1 = __shfl_down(A1, 1u, 64); eB1 = __shfl_down(B1, 1u, 64);
        if (lane == 63) { eA0 = 1.f; eB0 = 0.f; eA1 = 1.f; eB1 = 0.f; }
    }
    float H0 = fmaf(eA0, WB0, eB0);
    float H1 = fmaf(eA1, WB1, eB1);

    if (dir == 0) {
#pragma unroll
        for (int i = 0; i < 16; ++i) {
            H0 = fmaf(av0[i], H0, vv0[i]); vv0[i] = H0;
            H1 = fmaf(av1[i], H1, vv1[i]); vv1[i] = H1;
        }
    } else {
#pragma unroll
        for (int i = 15; i >= 0; --i) {
            H0 = fmaf(av0[i], H0, vv0[i]); vv0[i] = H0;
            H1 = fmaf(av1[i], H1, vv1[i]); vv1[i] = H1;
        }
    }

#pragma unroll
    for (int q = 0; q < 4; ++q) {
        const uint32_t g = lane * 4 + q;
        const uint32_t gs = g ^ ((g >> 3) & 7);
        *(float4*)&swf[gs * 4] =
            make_float4(vv0[q * 4], vv0[q * 4 + 1], vv0[q * 4 + 2], vv0[q * 4 + 3]);
        *(float4*)&swf[1024 + gs * 4] =
            make_float4(vv1[q * 4], vv1[q * 4 + 1], vv1[q * 4 + 2], vv1[q * 4 + 3]);
    }
    asm volatile("s_waitcnt lgkmcnt(0)" ::: "memory");
    const int c0 = 2 * p, c1 = 2 * p + 1;
    float* orow0 = out + ((size_t)b * 512 + dir * 256 + c0) * LSEQ + w * 1024;
    float* orow1 = out + ((size_t)b * 512 + dir * 256 + c1) * LSEQ + w * 1024;
#pragma unroll
    for (int i = 0; i < 4; ++i) {
        const uint32_t g = i * 64 + lane;
        const uint32_t gs = g ^ ((g >> 3) & 7);
        *(float4*)(orow0 + i * 256 + lane * 4) = *(const float4*)&swf[gs * 4];
        *(float4*)(orow1 + i * 256 + lane * 4) = *(const float4*)&swf[1024 + gs * 4];
    }
}

// ---------------- launch ----------------
extern "C" void kernel_launch(void* const* d_in, const int* in_sizes, int n_in,
                              void* d_out, int out_size, void* d_ws, size_t ws_size,
                              hipStream_t stream) {
    const float* x = (const float*)d_in[0];  // (8, 512, 8192)
    const float* W = (const float*)d_in[1];  // (1024, 512, 1)
    float* out = (float*)d_out;              // (8, 512, 8192)

    uint32_t* Wnb = (uint32_t*)d_ws;  // 1 MB
    uint32_t* fbp = (uint32_t*)((char*)d_ws + (size_t)NO * DIN * 2);  // 134 MB
    uint32_t* xp  = (uint32_t*)((char*)d_ws + (size_t)NO * DIN * 2
                                + (size_t)NB * 512 * LSEQ * 4);       // 64 MB

    norm_kernel<<<dim3(NO), dim3(64), 0, stream>>>(W, Wnb);
    xpack_kernel<<<dim3(512, NB), dim3(256), 0, stream>>>(x, xp);
    gemm_kernel<<<dim3(512, NB), dim3(256), 0, stream>>>((const uint32_t*)Wnb, xp, fbp);
    scan_kernel<<<dim3(256, NB), dim3(512), 0, stream>>>(fbp, out);
}

// Round 2
// 350.117 us; speedup vs baseline: 1.0426x; 1.0426x over previous
//
#include <hip/hip_runtime.h>
#include <math.h>
#include <stdint.h>

#define LSEQ 8192
#define DIN  512
#define NB   8
#define NO   1024

typedef __bf16 bf16x8 __attribute__((ext_vector_type(8)));
typedef float f32x16 __attribute__((ext_vector_type(16)));

__device__ __forceinline__ uint32_t pack_bf16_rne(float lo, float hi) {
    uint32_t ul = __builtin_bit_cast(uint32_t, lo);
    uint32_t uh = __builtin_bit_cast(uint32_t, hi);
    ul += 0x7FFFu + ((ul >> 16) & 1u);
    uh += 0x7FFFu + ((uh >> 16) & 1u);
    return (ul >> 16) | (uh & 0xFFFF0000u);
}
__device__ __forceinline__ float bf16_lo(uint32_t w) {
    return __builtin_bit_cast(float, w << 16);
}
__device__ __forceinline__ float bf16_hi(uint32_t w) {
    return __builtin_bit_cast(float, w & 0xFFFF0000u);
}

// async global->LDS, 16B per lane; LDS dest = wave-uniform base + lane*16
__device__ __forceinline__ void gl_lds16(const void* g, void* l) {
    __builtin_amdgcn_global_load_lds(
        (const __attribute__((address_space(1))) void*)g,
        (__attribute__((address_space(3))) void*)l, 16, 0, 0);
}

// Fragment-major tile layout (A and B identical structure):
//   per 128-row(col) x 512-k tile: 16 iter-slices of 2048 words; within a
//   slice, chunk c = ((mb*4 + q)*32 + m31) holds the 16B fragment for
//   row/col (mb*32+m31), k2-group q (k2 = it*16 + q*4 + wic).
//   A ds_read_b128 for (mb, kh) is then base + lane*16 -> conflict-free.

// ---------------- Kernel 1: weight norm -> bf16, fragment-major -----------
__global__ void norm_kernel(const float* __restrict__ W, uint32_t* __restrict__ Wnb) {
    const int o = blockIdx.x;
    const int lane = threadIdx.x;  // 0..63
    const float* row = W + (size_t)o * DIN;
    float4 v0 = *(const float4*)(row + lane * 4);
    float4 v1 = *(const float4*)(row + 256 + lane * 4);
    float s = v0.x * v0.x + v0.y * v0.y + v0.z * v0.z + v0.w * v0.w
            + v1.x * v1.x + v1.y * v1.y + v1.z * v1.z + v1.w * v1.w;
#pragma unroll
    for (int m = 32; m; m >>= 1) s += __shfl_xor(s, m, 64);
    const float sq = 22.62741699796952f;  // sqrt(512)
    const float scale = 1.0f / ((1e-4f + sqrtf(s) / sq) * sq);
    uint2 w0, w1;
    w0.x = pack_bf16_rne(v0.x * scale, v0.y * scale);
    w0.y = pack_bf16_rne(v0.z * scale, v0.w * scale);
    w1.x = pack_bf16_rne(v1.x * scale, v1.y * scale);
    w1.y = pack_bf16_rne(v1.z * scale, v1.w * scale);
    // w0 covers k2 = 2*lane, 2*lane+1 ; w1 covers k2 = 128 + 2*lane, +1
    const int ot = o >> 7, mb = (o >> 5) & 3, m31 = o & 31;
    const int it0 = lane >> 3;          // k2>>4
    const int q   = (lane >> 1) & 3;    // (k2>>2)&3
    const int wic = (lane & 1) * 2;     // k2&3
    uint32_t* base = Wnb + (size_t)ot * 32768 + ((mb * 4 + q) * 32 + m31) * 4 + wic;
    *(uint2*)&base[(size_t)it0 * 2048] = w0;
    *(uint2*)&base[(size_t)(it0 + 8) * 2048] = w1;
}

// ---------------- Kernel 1b: x fp32 -> pair-packed bf16, fragment-major ----
// Block handles one (b, lt, 32-k2 chunk): reads 32 KB coalesced, LDS
// transpose, writes fragment-major chunks (8x128B segments per wave).
__global__ __launch_bounds__(256)
void xpack_kernel(const float* __restrict__ x, uint32_t* __restrict__ xp) {
    __shared__ uint32_t sT[32 * 132];  // stride 132: 16B-aligned rows
    const int t  = threadIdx.x;
    const int bx = blockIdx.x;  // lt = bx>>3, ch = bx&7
    const int b  = blockIdx.y;
    const int lt = bx >> 3;
    const int ch = bx & 7;

    const float* xb = x + (size_t)b * DIN * LSEQ + lt * 128;
#pragma unroll
    for (int j = 0; j < 4; ++j) {
        const int idx = j * 256 + t;  // 0..1023
        const int k2l = idx >> 5;     // 0..31
        const int lg  = idx & 31;
        const float* r0 = xb + (size_t)(2 * (ch * 32 + k2l)) * LSEQ + lg * 4;
        float4 a = *(const float4*)r0;
        float4 c = *(const float4*)(r0 + LSEQ);
        uint4 wv;
        wv.x = pack_bf16_rne(a.x, c.x);
        wv.y = pack_bf16_rne(a.y, c.y);
        wv.z = pack_bf16_rne(a.z, c.z);
        wv.w = pack_bf16_rne(a.w, c.w);
        *(uint4*)&sT[k2l * 132 + lg * 4] = wv;
    }
    __syncthreads();
    uint32_t* ob = xp + (size_t)(b * 64 + lt) * 32768;
#pragma unroll
    for (int j = 0; j < 4; ++j) {
        const int idx = j * 256 + t;  // 0..1023
        const int lp  = idx >> 3;     // l' 0..127
        const int gq  = idx & 7;      // local k2 group of 4 (k2l = gq*4..+3)
        uint4 wv;
        wv.x = sT[(gq * 4 + 0) * 132 + lp];
        wv.y = sT[(gq * 4 + 1) * 132 + lp];
        wv.z = sT[(gq * 4 + 2) * 132 + lp];
        wv.w = sT[(gq * 4 + 3) * 132 + lp];
        const int itl   = ch * 2 + (gq >> 2);                 // k2>>4
        const int q     = gq & 3;                             // (k2>>2)&3
        const int chunk = ((lp >> 5) * 4 + q) * 32 + (lp & 31);
        *(uint4*)&ob[(size_t)itl * 2048 + chunk * 4] = wv;
    }
}

// ---------------- Kernel 2: bf16 MFMA GEMM, fragment-major LDS ------------
// fbp word (b, o2, l) = bf16 fb[b][2*o2][l] | bf16 fb[b][2*o2+1][l] << 16.
// Both A and B staged via global_load_lds, 1KB contiguous per instruction,
// linear LDS; all fragment reads are ds_read_b128 at base + lane*16.
__global__ __launch_bounds__(256)
void gemm_kernel(const uint32_t* __restrict__ Wnb, const uint32_t* __restrict__ xp,
                 uint32_t* __restrict__ fbp) {
    __shared__ uint32_t sA[2][2048];  // 2 x 8 KB
    __shared__ uint32_t sB[2][2048];  // 2 x 8 KB

    const int tid  = threadIdx.x;
    const int lane = tid & 63;
    const int w    = tid >> 6;
    const int wm   = w & 1, wn = w >> 1;

    const int bx  = blockIdx.x;
    const int xcd = bx & 7;
    const int t   = bx >> 3;
    const int o0t = t & 7;
    const int o0  = o0t * 128;
    const int ltg = xcd + ((t >> 3) << 3);
    const int l0  = ltg * 128;
    const int b   = blockIdx.y;

    // staging sources: contiguous 1KB per instruction (wave w stages
    // chunk-blocks j = 2w and 2w+1 of both A and B)
    const uint32_t* gA = Wnb + (size_t)o0t * 32768 + (w * 2) * 256 + lane * 4;
    const uint32_t* gB = xp + (size_t)(b * 64 + ltg) * 32768 + (w * 2) * 256 + lane * 4;

    f32x16 acc[2][2];
#pragma unroll
    for (int i = 0; i < 2; ++i)
#pragma unroll
        for (int j = 0; j < 2; ++j)
#pragma unroll
            for (int r = 0; r < 16; ++r) acc[i][j][r] = 0.f;

#define STAGE(it, bs)                                               \
    do {                                                            \
        gl_lds16(gA + (size_t)(it) * 2048, &sA[bs][w * 512]);       \
        gl_lds16(gA + (size_t)(it) * 2048 + 256, &sA[bs][w * 512 + 256]); \
        gl_lds16(gB + (size_t)(it) * 2048, &sB[bs][w * 512]);       \
        gl_lds16(gB + (size_t)(it) * 2048 + 256, &sB[bs][w * 512 + 256]); \
    } while (0)

    STAGE(0, 0);
#pragma unroll 2
    for (int it = 0; it < 16; ++it) {
        const int cb = it & 1;
        __syncthreads();  // drains vmcnt(0): buf[cb] ready, prev compute done
        if (it + 1 < 16) STAGE(it + 1, cb ^ 1);
        const uint32_t* cA = sA[cb];
        const uint32_t* cB = sB[cb];
#pragma unroll
        for (int kh = 0; kh < 2; ++kh) {
            bf16x8 af[2], bfr[2];
#pragma unroll
            for (int ms = 0; ms < 2; ++ms)
                af[ms] = *(const bf16x8*)&cA[((wm * 2 + ms) * 4 + kh * 2) * 128 + lane * 4];
#pragma unroll
            for (int ns = 0; ns < 2; ++ns)
                bfr[ns] = *(const bf16x8*)&cB[((wn * 2 + ns) * 4 + kh * 2) * 128 + lane * 4];
#pragma unroll
            for (int ms = 0; ms < 2; ++ms)
#pragma unroll
                for (int ns = 0; ns < 2; ++ns)
                    acc[ms][ns] = __builtin_amdgcn_mfma_f32_32x32x16_bf16(
                        af[ms], bfr[ns], acc[ms][ns], 0, 0, 0);
        }
    }
#undef STAGE

    // epilogue: pack adjacent-o pairs (adjacent acc regs) -> one uint32 word
    uint32_t* fbp_b = fbp + (size_t)b * 512 * LSEQ + l0;
#pragma unroll
    for (int ms = 0; ms < 2; ++ms)
#pragma unroll
        for (int ns = 0; ns < 2; ++ns) {
            const f32x16 a = acc[ms][ns];
            const int rb = o0 + wm * 64 + ms * 32 + 4 * (lane >> 5);  // even
            const int cc = wn * 64 + ns * 32 + (lane & 31);
#pragma unroll
            for (int rp = 0; rp < 8; ++rp) {
                const int r = rp * 2;
                const int row = rb + (r & 3) + 8 * (r >> 2);  // even
                fbp_b[(size_t)(row >> 1) * LSEQ + cc] = pack_bf16_rne(a[r], a[r + 1]);
            }
        }
}

// ---------------- Kernel 3: minGRU scan over o-pair-packed bf16 fb --------
__global__ __launch_bounds__(512)
void scan_kernel(const uint32_t* __restrict__ fbp, float* __restrict__ out) {
    __shared__ uint32_t sbuf[8][2048];  // 64 KB
    __shared__ float sA0[8], sB0[8], sA1[8], sB1[8];

    const int bx  = blockIdx.x;  // 0..255
    const int b   = blockIdx.y;
    const int dir = bx >> 7;
    const int p   = bx & 127;
    const int o2h = dir * 256 + p;
    const int o2g = dir * 256 + 128 + p;

    const int t    = threadIdx.x;
    const int lane = t & 63;
    const int w    = t >> 6;

    const uint32_t* hwp = fbp + ((size_t)b * 512 + o2h) * LSEQ + w * 1024;
    const uint32_t* gwp = fbp + ((size_t)b * 512 + o2g) * LSEQ + w * 1024;
    uint32_t* sw = sbuf[w];
    float* swf = (float*)sbuf[w];

#pragma unroll
    for (int i = 0; i < 4; ++i) {
        uint4 v = *(const uint4*)(hwp + i * 256 + lane * 4);
        const uint32_t g = i * 64 + lane;
        const uint32_t gs = g ^ ((g >> 3) & 7);
        *(uint4*)&sw[gs * 4] = v;
    }
#pragma unroll
    for (int i = 0; i < 4; ++i) {
        uint4 v = *(const uint4*)(gwp + i * 256 + lane * 4);
        const uint32_t g = i * 64 + lane;
        const uint32_t gs = g ^ ((g >> 3) & 7);
        *(uint4*)&sw[1024 + gs * 4] = v;
    }
    asm volatile("s_waitcnt lgkmcnt(0)" ::: "memory");

    float av0[16], vv0[16], av1[16], vv1[16];
#pragma unroll
    for (int q = 0; q < 4; ++q) {
        const uint32_t g = lane * 4 + q;
        const uint32_t gs = g ^ ((g >> 3) & 7);
        uint4 hw4 = *(const uint4*)&sw[gs * 4];
        uint4 gw4 = *(const uint4*)&sw[1024 + gs * 4];
        const uint32_t hws[4] = {hw4.x, hw4.y, hw4.z, hw4.w};
        const uint32_t gws[4] = {gw4.x, gw4.y, gw4.z, gw4.w};
#pragma unroll
        for (int s = 0; s < 4; ++s) {
            const int mo = q * 4 + s;
            {
                float g_ = fminf(fmaxf(bf16_lo(gws[s]), -30.f), 30.f);
                float eg = __expf(g_);
                float a  = rsqrtf(fmaf(eg, eg, 1.f));
                float h_ = bf16_lo(hws[s]);
                av0[mo] = a;
                vv0[mo] = a * eg * copysignf(fmaxf(fabsf(h_), 1e-6f), h_);
            }
            {
                float g_ = fminf(fmaxf(bf16_hi(gws[s]), -30.f), 30.f);
                float eg = __expf(g_);
                float a  = rsqrtf(fmaf(eg, eg, 1.f));
                float h_ = bf16_hi(hws[s]);
                av1[mo] = a;
                vv1[mo] = a * eg * copysignf(fmaxf(fabsf(h_), 1e-6f), h_);
            }
        }
    }

    float A0 = 1.f, B0 = 0.f, A1 = 1.f, B1 = 0.f;
    if (dir == 0) {
#pragma unroll
        for (int i = 0; i < 16; ++i) {
            B0 = fmaf(av0[i], B0, vv0[i]); A0 *= av0[i];
            B1 = fmaf(av1[i], B1, vv1[i]); A1 *= av1[i];
        }
    } else {
#pragma unroll
        for (int i = 15; i >= 0; --i) {
            B0 = fmaf(av0[i], B0, vv0[i]); A0 *= av0[i];
            B1 = fmaf(av1[i], B1, vv1[i]); A1 *= av1[i];
        }
    }

    if (dir == 0) {
#pragma unroll
        for (int off = 1; off < 64; off <<= 1) {
            float Ap0 = __shfl_up(A0, (unsigned)off, 64), Bp0 = __shfl_up(B0, (unsigned)off, 64);
            float Ap1 = __shfl_up(A1, (unsigned)off, 64), Bp1 = __shfl_up(B1, (unsigned)off, 64);
            if (lane >= off) {
                B0 = fmaf(A0, Bp0, B0); A0 *= Ap0;
                B1 = fmaf(A1, Bp1, B1); A1 *= Ap1;
            }
        }
        if (lane == 63) { sA0[w] = A0; sB0[w] = B0; sA1[w] = A1; sB1[w] = B1; }
    } else {
#pragma unroll
        for (int off = 1; off < 64; off <<= 1) {
            float Ap0 = __shfl_down(A0, (unsigned)off, 64), Bp0 = __shfl_down(B0, (unsigned)off, 64);
            float Ap1 = __shfl_down(A1, (unsigned)off, 64), Bp1 = __shfl_down(B1, (unsigned)off, 64);
            if (lane + off < 64) {
                B0 = fmaf(A0, Bp0, B0); A0 *= Ap0;
                B1 = fmaf(A1, Bp1, B1); A1 *= Ap1;
            }
        }
        if (lane == 0) { sA0[w] = A0; sB0[w] = B0; sA1[w] = A1; sB1[w] = B1; }
    }
    __syncthreads();
    float WB0 = 0.f, WB1 = 0.f;
    if (dir == 0) {
        for (int wv = 0; wv < w; ++wv) {
            WB0 = fmaf(sA0[wv], WB0, sB0[wv]);
            WB1 = fmaf(sA1[wv], WB1, sB1[wv]);
        }
    } else {
        for (int wv = 7; wv > w; --wv) {
            WB0 = fmaf(sA0[wv], WB0, sB0[wv]);
            WB1 = fmaf(sA1[wv], WB1, sB1[wv]);
        }
    }
    float eA0, eB0, eA1, eB1;
    if (dir == 0) {
        eA0 = __shfl_up(A0, 1u, 64); eB0 = __shfl_up(B0, 1u, 64);
        eA1 = __shfl_up(A1, 1u, 64); eB1 = __shfl_up(B1, 1u, 64);
        if (lane == 0) { eA0 = 1.f; eB0 = 0.f; eA1 = 1.f; eB1 = 0.f; }
    } else {
        eA0 = __shfl_down(A0, 1u, 64); eB0 = __shfl_down(B0, 1u, 64);
        eA1 = __shfl_down(A1, 1u, 64); eB1 = __shfl_down(B1, 1u, 64);
        if (lane == 63) { eA0 = 1.f; eB0 = 0.f; eA1 = 1.f; eB1 = 0.f; }
    }
    float H0 = fmaf(eA0, WB0, eB0);
    float H1 = fmaf(eA1, WB1, eB1);

    if (dir == 0) {
#pragma unroll
        for (int i = 0; i < 16; ++i) {
            H0 = fmaf(av0[i], H0, vv0[i]); vv0[i] = H0;
            H1 = fmaf(av1[i], H1, vv1[i]); vv1[i] = H1;
        }
    } else {
#pragma unroll
        for (int i = 15; i >= 0; --i) {
            H0 = fmaf(av0[i], H0, vv0[i]); vv0[i] = H0;
            H1 = fmaf(av1[i], H1, vv1[i]); vv1[i] = H1;
        }
    }

#pragma unroll
    for (int q = 0; q < 4; ++q) {
        const uint32_t g = lane * 4 + q;
        const uint32_t gs = g ^ ((g >> 3) & 7);
        *(float4*)&swf[gs * 4] =
            make_float4(vv0[q * 4], vv0[q * 4 + 1], vv0[q * 4 + 2], vv0[q * 4 + 3]);
        *(float4*)&swf[1024 + gs * 4] =
            make_float4(vv1[q * 4], vv1[q * 4 + 1], vv1[q * 4 + 2], vv1[q * 4 + 3]);
    }
    asm volatile("s_waitcnt lgkmcnt(0)" ::: "memory");
    const int c0 = 2 * p, c1 = 2 * p + 1;
    float* orow0 = out + ((size_t)b * 512 + dir * 256 + c0) * LSEQ + w * 1024;
    float* orow1 = out + ((size_t)b * 512 + dir * 256 + c1) * LSEQ + w * 1024;
#pragma unroll
    for (int i = 0; i < 4; ++i) {
        const uint32_t g = i * 64 + lane;
        const uint32_t gs = g ^ ((g >> 3) & 7);
        *(float4*)(orow0 + i * 256 + lane * 4) = *(const float4*)&swf[gs * 4];
        *(float4*)(orow1 + i * 256 + lane * 4) = *(const float4*)&swf[1024 + gs * 4];
    }
}

// ---------------- launch ----------------
extern "C" void kernel_launch(void* const* d_in, const int* in_sizes, int n_in,
                              void* d_out, int out_size, void* d_ws, size_t ws_size,
                              hipStream_t stream) {
    const float* x = (const float*)d_in[0];  // (8, 512, 8192)
    const float* W = (const float*)d_in[1];  // (1024, 512, 1)
    float* out = (float*)d_out;              // (8, 512, 8192)

    uint32_t* Wnb = (uint32_t*)d_ws;  // 1 MB
    uint32_t* fbp = (uint32_t*)((char*)d_ws + (size_t)NO * DIN * 2);  // 134 MB
    uint32_t* xp  = (uint32_t*)((char*)d_ws + (size_t)NO * DIN * 2
                                + (size_t)NB * 512 * LSEQ * 4);       // 64 MB

    norm_kernel<<<dim3(NO), dim3(64), 0, stream>>>(W, Wnb);
    xpack_kernel<<<dim3(512, NB), dim3(256), 0, stream>>>(x, xp);
    gemm_kernel<<<dim3(512, NB), dim3(256), 0, stream>>>(Wnb, xp, fbp);
    scan_kernel<<<dim3(256, NB), dim3(512), 0, stream>>>(fbp, out);
}